// Round 19
// baseline (221.888 us; speedup 1.0000x reference)
//
#include <hip/hip_runtime.h>
#include <math.h>
#include <stdint.h>

constexpr int BB = 16384;   // batch
constexpr int NF = 39;      // fields
constexpr int NE = 16;      // embed dim
constexpr int ND = NF * NE; // 624
constexpr int FIELD_DIM = 26000;
constexpr float EPS_ = 1e-5f;

typedef __bf16 bfx8 __attribute__((ext_vector_type(8)));
typedef float f32x4 __attribute__((ext_vector_type(4)));
typedef short s16x8 __attribute__((ext_vector_type(8)));

static __device__ __forceinline__ unsigned short f2bf(float f) {
    union { float f; unsigned u; } a; a.f = f;
    unsigned r = a.u + 0x7fffu + ((a.u >> 16) & 1u); // RNE
    return (unsigned short)(r >> 16);
}
static __device__ __forceinline__ float bf2f(unsigned short u) {
    union { unsigned u; float f; } a; a.u = ((unsigned)u) << 16;
    return a.f;
}

// XCD-aware block remap: l -> (bx, by). ny must be 128 (=8 XCDs * 16 panels).
static __device__ __forceinline__ void xcd_map(int l, int lognx, int& bx, int& by) {
    int s = l >> 3;
    bx = s & ((1 << lognx) - 1);
    by = ((l & 7) << 4) + (s >> lognx);
}

// ---------------- merged prep + field-BN stats ----------------
// blocks [0,2496): field stats | [2496,3776): w transposes | [3776,3893): wct
__global__ void k_prep_stats(const int* __restrict__ x, const float* __restrict__ emb,
                             const float* __restrict__ w1, const float* __restrict__ w2,
                             const float* __restrict__ w3, const float* __restrict__ cw,
                             unsigned short* __restrict__ w1t, unsigned short* __restrict__ w2t,
                             unsigned short* __restrict__ w3t, float* __restrict__ wct,
                             double* __restrict__ stats_f) {
    __shared__ double ls[256], lq[256];
    __shared__ float tile[32][33];
    int b = blockIdx.x;
    if (b < 2496) {                       // field stats: f = b%NF, chunk = b/NF
        int f = b % NF;
        int r = (b / NF) * 256 + threadIdx.x;
        double s = 0.0, q = 0.0;
        {
            long long id = (long long)x[r * NF + f] + (long long)f * FIELD_DIM;
            const float4* p = (const float4*)(emb + id * NE);
#pragma unroll
            for (int i = 0; i < 4; ++i) {
                float4 v = p[i];
                s += (double)v.x; s += (double)v.y; s += (double)v.z; s += (double)v.w;
                q += (double)v.x * v.x; q += (double)v.y * v.y;
                q += (double)v.z * v.z; q += (double)v.w * v.w;
            }
        }
        ls[threadIdx.x] = s; lq[threadIdx.x] = q;
        __syncthreads();
        for (int off = 128; off > 0; off >>= 1) {
            if ((int)threadIdx.x < off) {
                ls[threadIdx.x] += ls[threadIdx.x + off];
                lq[threadIdx.x] += lq[threadIdx.x + off];
            }
            __syncthreads();
        }
        if (threadIdx.x == 0) {
            atomicAdd(&stats_f[f], ls[0]);
            atomicAdd(&stats_f[NF + f], lq[0]);
        }
    } else if (b < 3776) {                // LDS-tiled weight transposes
        int bb = b - 2496;
        const float* in; unsigned short* outp; int K, N, Kpad, tid;
        if (bb < 640)       { in = w1; outp = w1t; K = 624;  N = 1024; Kpad = 640;  tid = bb; }
        else if (bb < 1152) { in = w2; outp = w2t; K = 1024; N = 512;  Kpad = 1024; tid = bb - 640; }
        else                { in = w3; outp = w3t; K = 512;  N = 256;  Kpad = 512;  tid = bb - 1152; }
        int tiles_n = N >> 5;
        int tk = tid / tiles_n, tn = tid % tiles_n;
        int tx = threadIdx.x & 31, ty = threadIdx.x >> 5;  // 32 x 8
#pragma unroll
        for (int i = 0; i < 4; ++i) {
            int k = tk * 32 + ty + i * 8, n = tn * 32 + tx;
            tile[ty + i * 8][tx] = (k < K) ? in[(size_t)k * N + n] : 0.f;
        }
        __syncthreads();
#pragma unroll
        for (int i = 0; i < 4; ++i) {
            int n = tn * 32 + ty + i * 8, k = tk * 32 + tx;
            outp[(size_t)n * Kpad + k] = f2bf(tile[tx][ty + i * 8]);
        }
    } else {                              // wct: (48, 624) fp32, rows>=39 zero
        int gid = (b - 3776) * 256 + threadIdx.x;
        if (gid < 48 * ND) {
            int j = gid / ND, k = gid % ND;
            wct[gid] = (j < NF) ? cw[(size_t)k * NF + j] : 0.f;
        }
    }
}

// ---------------- controller GEMM split-K x4, gather-fused A ----------------
__launch_bounds__(256)
__global__ void k_ctrl_gemm_sk(const int* __restrict__ x, const float* __restrict__ emb,
                               const double* __restrict__ stats_f,
                               const float* __restrict__ bng, const float* __restrict__ bnb,
                               const float* __restrict__ wct, double* __restrict__ zp) {
    __shared__ float As[64][68];       // [row][kk], padded
    __shared__ float Ws[64][49];       // [kk][col]
    __shared__ int xoff[64 * NF];      // per-(row,field) emb float-offset
    __shared__ float fsc[NF], fsh[NF];
    const int t = threadIdx.x;
    const int tn = t & 15;             // col group: cols 3tn..3tn+2
    const int tm = t >> 4;             // row group: rows 4tm..4tm+3
    const int bm = blockIdx.x & 255;
    const int qt = blockIdx.x >> 8;    // 0..3
    const int m0 = bm * 64;
    const int kbq[5] = {0, 192, 320, 512, 624};
    const int kbeg = kbq[qt];
    const int kend = kbq[qt + 1];

    if (t < NF) {
        double cnt = (double)BB * NE;
        double mu = stats_f[t] / cnt;
        double var = stats_f[NF + t] / cnt - mu * mu;
        float sc = (float)((double)bng[t] / sqrt(var + (double)EPS_));
        fsc[t] = sc;
        fsh[t] = bnb[t] - (float)mu * sc;
    }
    const int* xrow = x + m0 * NF;
    for (int j = t; j < 64 * NF; j += 256) {
        int f = j % NF;
        xoff[j] = (xrow[j] + f * FIELD_DIM) * NE;
    }
    __syncthreads();

    double acc[4][3] = {};
    for (int k0 = kbeg; k0 < kend; k0 += 64) {
        const int kl = (kend - k0 >= 64) ? 64 : (kend - k0);   // 64 or 48
        const int kl4 = kl >> 2;
#pragma unroll
        for (int i = 0; i < 4; ++i) {
            int idx = t + 256 * i;     // 0..1023
            int row = idx >> 4, c4 = idx & 15;
            if (c4 < kl4) {
                int k = k0 + c4 * 4;
                int f = k >> 4;
                float4 v = *(const float4*)(emb + xoff[row * NF + f] + (k & 12));
                float sc = fsc[f], sh = fsh[f];
                float4 nv = make_float4(fmaf(v.x, sc, sh), fmaf(v.y, sc, sh),
                                        fmaf(v.z, sc, sh), fmaf(v.w, sc, sh));
                *(float4*)&As[row][c4 * 4] = nv;
            }
        }
        {
            int col = t >> 4;          // 0..15
            int c4 = t & 15;
#pragma unroll
            for (int cp = 0; cp < 3; ++cp, col += 16) {
                if (c4 < kl4) {
                    float4 v = *(const float4*)(wct + (size_t)col * ND + k0 + c4 * 4);
                    Ws[c4 * 4 + 0][col] = v.x; Ws[c4 * 4 + 1][col] = v.y;
                    Ws[c4 * 4 + 2][col] = v.z; Ws[c4 * 4 + 3][col] = v.w;
                }
            }
        }
        __syncthreads();
#pragma unroll 4
        for (int kk = 0; kk < kl; ++kk) {
            double a0 = (double)As[4 * tm + 0][kk];
            double a1 = (double)As[4 * tm + 1][kk];
            double a2 = (double)As[4 * tm + 2][kk];
            double a3 = (double)As[4 * tm + 3][kk];
            double w0 = (double)Ws[kk][3 * tn + 0];
            double w1 = (double)Ws[kk][3 * tn + 1];
            double w2 = (double)Ws[kk][3 * tn + 2];
            acc[0][0] += a0 * w0; acc[0][1] += a0 * w1; acc[0][2] += a0 * w2;
            acc[1][0] += a1 * w0; acc[1][1] += a1 * w1; acc[1][2] += a1 * w2;
            acc[2][0] += a2 * w0; acc[2][1] += a2 * w1; acc[2][2] += a2 * w2;
            acc[3][0] += a3 * w0; acc[3][1] += a3 * w1; acc[3][2] += a3 * w2;
        }
        __syncthreads();
    }
    double* zph = zp + (size_t)qt * BB * NF;
#pragma unroll
    for (int j = 0; j < 3; ++j) {
        int col = 3 * tn + j;
        if (col < NF) {
#pragma unroll
            for (int i = 0; i < 4; ++i)
                zph[(size_t)(m0 + 4 * tm + i) * NF + col] = acc[i][j];
        }
    }
}

// ---------------- split-K reduce: z = (float)(((p0+p1)+(p2+p3))+bias), fused col stats --------
__global__ void k_ctrl_reduce(const double* __restrict__ zp, const float* __restrict__ bias,
                              float* __restrict__ z, double* __restrict__ stats) {
    __shared__ double Sred[2][16][48];
    const int t = threadIdx.x;
    const int tn = t & 15;
    const int tm = t >> 4;
    const int m0 = blockIdx.x * 64;
    const size_t H = (size_t)BB * NF;
#pragma unroll
    for (int j = 0; j < 3; ++j) {
        int col = 3 * tn + j;
        double s = 0.0, q = 0.0;
        if (col < NF) {
            float bs = bias[col];
#pragma unroll
            for (int i = 0; i < 4; ++i) {
                size_t idx = (size_t)(m0 + 4 * tm + i) * NF + col;
                double p01 = (zp[idx] + zp[H + idx]) + (zp[2 * H + idx] + zp[3 * H + idx]);
                float v = (float)(p01 + (double)bs);
                z[idx] = v;
                s += (double)v;
                q += (double)v * (double)v;
            }
        }
        Sred[0][tm][col] = s;
        Sred[1][tm][col] = q;
    }
    __syncthreads();
    if (t < NF) {
        double ts = 0.0, tq = 0.0;
#pragma unroll
        for (int i = 0; i < 16; ++i) { ts += Sred[0][i][t]; tq += Sred[1][i][t]; }
        atomicAdd(&stats[t], ts);
        atomicAdd(&stats[NF + t], tq);
    }
}

// ---------------- ctrl-BN finalize + BN+ReLU + rank top-k + gather-gate -> flatg (fused) --------
__global__ void k_topk_gate(const float* __restrict__ zc, const double* __restrict__ stats,
                            const float* __restrict__ cbg, const float* __restrict__ cbb,
                            const int* __restrict__ kptr, const int* __restrict__ x,
                            const float* __restrict__ emb, const double* __restrict__ stats_f,
                            const float* __restrict__ bng, const float* __restrict__ bnb,
                            unsigned short* __restrict__ flatg) {
    __shared__ float sc_s[NF], sh_s[NF], fsc[NF], fsh[NF];
    int t = threadIdx.x;
    if (t < NF) {
        double mu = stats[t] / (double)BB;
        double var = stats[NF + t] / (double)BB - mu * mu;
        float sc = (float)((double)cbg[t] / sqrt(var + (double)EPS_));
        sc_s[t] = sc;
        sh_s[t] = cbb[t] - (float)mu * sc;
        double cnt = (double)BB * NE;
        double muf = stats_f[t] / cnt;
        double varf = stats_f[NF + t] / cnt - muf * muf;
        float scf = (float)((double)bng[t] / sqrt(varf + (double)EPS_));
        fsc[t] = scf;
        fsh[t] = bnb[t] - (float)muf * scf;
    }
    __syncthreads();
    int r = blockIdx.x * 4 + (t >> 6);
    int lane = t & 63;
    int k = kptr[0];
    bool active = (lane < NF);
    float w = -1.f;
    if (active) {
        float v = zc[(size_t)r * NF + lane];
        w = fmaxf(fmaf(v, sc_s[lane], sh_s[lane]), 0.f);
    }
    int rank = 0;
#pragma unroll
    for (int j = 0; j < NF; ++j) {
        float vj = __shfl(w, j, 64);
        rank += (vj > w || (vj == w && j < lane)) ? 1 : 0;
    }
    bool sel = active && (rank < k);
    float val = sel ? w : 0.f;
    float sum = val;
#pragma unroll
    for (int off = 32; off > 0; off >>= 1) sum += __shfl_xor(sum, off, 64);
    if (active) {
        float ms = sel ? ((sum > 0.f) ? (w / sum) : 0.f) : 0.f;
        int o = (x[r * NF + lane] + lane * FIELD_DIM) * NE;
        const float4* pe = (const float4*)(emb + o);
        float sc = fsc[lane], sh = fsh[lane];
        unsigned short* dst = flatg + (size_t)r * 640 + lane * 16;
#pragma unroll
        for (int h = 0; h < 2; ++h) {
            float4 e0 = pe[h * 2], e1 = pe[h * 2 + 1];
            float e[8] = {e0.x, e0.y, e0.z, e0.w, e1.x, e1.y, e1.z, e1.w};
            union { s16x8 v; unsigned short u[8]; } p;
#pragma unroll
            for (int j = 0; j < 8; ++j)
                p.u[j] = f2bf(fmaf(e[j], sc, sh) * ms);   // same op order as flat path
            *(s16x8*)(dst + h * 8) = p.v;
        }
    } else if (lane == NF) {
        s16x8 zv = {};
        *(s16x8*)(flatg + (size_t)r * 640 + 624) = zv;
        *(s16x8*)(flatg + (size_t)r * 640 + 632) = zv;
    }
}

// ---------------- bf16 MFMA GEMM (layer 1): 2-phase double-buffered, BK=64 (unchanged) --------
__launch_bounds__(256)
__global__ void k_mfma_gemm(const unsigned short* __restrict__ A,  // M x K bf16
                            const unsigned short* __restrict__ Bt, // N x K bf16
                            const float* __restrict__ bias,
                            unsigned short* __restrict__ C,        // M x N bf16
                            double* __restrict__ stats,            // 2*N fp64
                            int M, int K, int N, int lognx) {
    __shared__ char lds[65536];   // A0 A1 B0 B1, 16KB each
    const int t = threadIdx.x;
    const int l = t & 63;
    const int w = t >> 6;
    int bx, by;
    xcd_map(blockIdx.x, lognx, bx, by);
    const int m0 = by * 128, n0 = bx * 128;
    const int Wr = (w >> 1) * 64, Wc = (w & 1) * 64;

    const int srow = t >> 3;            // 0..31
    const int sswz = (t & 7) ^ (srow & 7);
    const unsigned short* ga[4];
    const unsigned short* gb[4];
#pragma unroll
    for (int i = 0; i < 4; ++i) {
        ga[i] = A + (size_t)(m0 + i * 32 + srow) * K + sswz * 8;
        gb[i] = Bt + (size_t)(n0 + i * 32 + srow) * K + sswz * 8;
    }
    int a_off[4][2], b_off[4][2];
#pragma unroll
    for (int m = 0; m < 4; ++m) {
#pragma unroll
        for (int h = 0; h < 2; ++h) {
            int r = Wr + m * 16 + (l & 15);
            a_off[m][h] = r * 128 + (((h * 4 + (l >> 4)) ^ (r & 7)) << 4);
            int c = Wc + m * 16 + (l & 15);
            b_off[m][h] = c * 128 + (((h * 4 + (l >> 4)) ^ (c & 7)) << 4);
        }
    }
    const int nt = K >> 6;
    f32x4 acc[4][4] = {};
#pragma unroll
    for (int i = 0; i < 4; ++i) {
        __builtin_amdgcn_global_load_lds(
            (const __attribute__((address_space(1))) void*)ga[i],
            (__attribute__((address_space(3))) void*)(lds + i * 4096 + t * 16), 16, 0, 0);
        __builtin_amdgcn_global_load_lds(
            (const __attribute__((address_space(1))) void*)gb[i],
            (__attribute__((address_space(3))) void*)(lds + 32768 + i * 4096 + t * 16), 16, 0, 0);
        ga[i] += 64; gb[i] += 64;
    }
    __syncthreads();
    for (int ts = 0; ts < nt; ++ts) {
        const int cur = ts & 1;
        if (ts + 1 < nt) {
            char* An = lds + (cur ^ 1) * 16384;
            char* Bn = lds + 32768 + (cur ^ 1) * 16384;
#pragma unroll
            for (int i = 0; i < 4; ++i) {
                __builtin_amdgcn_global_load_lds(
                    (const __attribute__((address_space(1))) void*)ga[i],
                    (__attribute__((address_space(3))) void*)(An + i * 4096 + t * 16), 16, 0, 0);
                __builtin_amdgcn_global_load_lds(
                    (const __attribute__((address_space(1))) void*)gb[i],
                    (__attribute__((address_space(3))) void*)(Bn + i * 4096 + t * 16), 16, 0, 0);
                ga[i] += 64; gb[i] += 64;
            }
        }
        const char* Ac = lds + cur * 16384;
        const char* Bc = lds + 32768 + cur * 16384;
        __builtin_amdgcn_s_setprio(1);
#pragma unroll
        for (int h = 0; h < 2; ++h) {
            bfx8 af[4], bv[4];
#pragma unroll
            for (int m = 0; m < 4; ++m)
                af[m] = __builtin_bit_cast(bfx8, *(const s16x8*)(Ac + a_off[m][h]));
#pragma unroll
            for (int n = 0; n < 4; ++n)
                bv[n] = __builtin_bit_cast(bfx8, *(const s16x8*)(Bc + b_off[n][h]));
#pragma unroll
            for (int m = 0; m < 4; ++m)
#pragma unroll
                for (int n = 0; n < 4; ++n)
                    acc[m][n] = __builtin_amdgcn_mfma_f32_16x16x32_bf16(af[m], bv[n], acc[m][n], 0, 0, 0);
        }
        __builtin_amdgcn_s_setprio(0);
        __syncthreads();
    }
#pragma unroll
    for (int n = 0; n < 4; ++n) {
        int nc = n0 + Wc + n * 16 + (l & 15);
        float bs = bias[nc];
        double s = 0.0, q = 0.0;
#pragma unroll
        for (int m = 0; m < 4; ++m) {
            int rbase = m0 + Wr + m * 16 + ((l >> 4) << 2);
#pragma unroll
            for (int i = 0; i < 4; ++i) {
                float v = acc[m][n][i] + bs;
                C[(size_t)(rbase + i) * N + nc] = f2bf(v);
                s += (double)v;
                q += (double)v * (double)v;
            }
        }
        s += __shfl_xor(s, 16, 64); s += __shfl_xor(s, 32, 64);
        q += __shfl_xor(q, 16, 64); q += __shfl_xor(q, 32, 64);
        if ((l >> 4) == 0) {
            atomicAdd(&stats[nc], s);
            atomicAdd(&stats[N + nc], q);
        }
    }
}

// ---------------- bf16 MFMA GEMM + fused input-BN (layers 2,3): BK=32, 40KB LDS, 4 blocks/CU ----
// 2-phase double-buffer; identical k-order per accumulator (chunks of 32, sequential) -> bit-identical.
// Layout: 64B rows; linear t*16 dest; source k-slot pre-swizzled (t&3)^((t>>2)&3);
// fragment reads r*64 + (((l>>4)^(r&3))<<4).
__launch_bounds__(256)
__global__ void k_mfma_gemm_bn(const unsigned short* __restrict__ A,   // M x K bf16 raw
                               const double* __restrict__ statsIn,     // 2*K (A's BN stats)
                               const float* __restrict__ g, const float* __restrict__ be,
                               const unsigned short* __restrict__ Bt,  // N x K bf16
                               const float* __restrict__ bias,
                               unsigned short* __restrict__ C,         // M x N bf16
                               double* __restrict__ stats,             // 2*N fp64
                               int M, int K, int N, int lognx) {
    __shared__ char lds[40960];           // A0 A1 B0 B1 (8KB each) + scs/shs (8KB)
    float* scs = (float*)(lds + 32768);   // K floats
    float* shs = scs + K;                 // K floats (K<=1024 -> fits 8KB)
    const int t = threadIdx.x;
    const int l = t & 63;
    const int w = t >> 6;
    int bx, by;
    xcd_map(blockIdx.x, lognx, bx, by);
    const int m0 = by * 128, n0 = bx * 128;
    const int Wr = (w >> 1) * 64, Wc = (w & 1) * 64;

    constexpr double inv_bb = 1.0 / (double)BB;
    for (int c = t; c < K; c += 256) {
        double mu = statsIn[c] * inv_bb;
        double var = statsIn[K + c] * inv_bb - mu * mu;
        float sc = g[c] / sqrtf((float)var + EPS_);
        scs[c] = sc;
        shs[c] = be[c] - (float)mu * sc;
    }
    __syncthreads();

    const int srow = t >> 2;            // 0..63
    const int sswz = (t & 3) ^ (srow & 3);
    const unsigned short* ga[2];
    const unsigned short* gb[2];
#pragma unroll
    for (int i = 0; i < 2; ++i) {
        ga[i] = A + (size_t)(m0 + i * 64 + srow) * K + sswz * 8;
        gb[i] = Bt + (size_t)(n0 + i * 64 + srow) * K + sswz * 8;
    }
    int a_off[4], b_off[4];
#pragma unroll
    for (int m = 0; m < 4; ++m) {
        int r = Wr + m * 16 + (l & 15);
        a_off[m] = r * 64 + (((l >> 4) ^ (r & 3)) << 4);
        int c = Wc + m * 16 + (l & 15);
        b_off[m] = c * 64 + (((l >> 4) ^ (c & 3)) << 4);
    }
    const int nt = K >> 5;
    f32x4 acc[4][4] = {};
    s16x8 praw[2];

    auto write_a = [&](int buf, int kb0) {
        char* Ad = lds + buf * 8192;
        int kb = kb0 + sswz * 8;
        float4 sc0 = *(const float4*)&scs[kb];
        float4 sc1 = *(const float4*)&scs[kb + 4];
        float4 sh0 = *(const float4*)&shs[kb];
        float4 sh1 = *(const float4*)&shs[kb + 4];
        float scl[8] = {sc0.x, sc0.y, sc0.z, sc0.w, sc1.x, sc1.y, sc1.z, sc1.w};
        float shl[8] = {sh0.x, sh0.y, sh0.z, sh0.w, sh1.x, sh1.y, sh1.z, sh1.w};
#pragma unroll
        for (int i = 0; i < 2; ++i) {
            union { s16x8 v; unsigned short u[8]; } pin;
            pin.v = praw[i];
            float f[8];
#pragma unroll
            for (int j = 0; j < 8; ++j)
                f[j] = fmaxf(fmaf(bf2f(pin.u[j]), scl[j], shl[j]), 0.f);
            union { unsigned w4[4]; s16x8 v; } pout;
#pragma unroll
            for (int j = 0; j < 4; ++j) {
                unsigned rr;
                asm("v_cvt_pk_bf16_f32 %0, %1, %2" : "=v"(rr) : "v"(f[2 * j]), "v"(f[2 * j + 1]));
                pout.w4[j] = rr;
            }
            *(s16x8*)(Ad + i * 4096 + t * 16) = pout.v;   // linear dest == row*64 + (t&3)*16
        }
    };
    auto load_praw = [&]() {
#pragma unroll
        for (int i = 0; i < 2; ++i) { praw[i] = *(const s16x8*)ga[i]; ga[i] += 32; }
    };
    auto stage_b = [&](int buf) {
        char* Bd = lds + 16384 + buf * 8192;
#pragma unroll
        for (int i = 0; i < 2; ++i) {
            __builtin_amdgcn_global_load_lds(
                (const __attribute__((address_space(1))) void*)gb[i],
                (__attribute__((address_space(3))) void*)(Bd + i * 4096 + t * 16), 16, 0, 0);
            gb[i] += 32;
        }
    };

    load_praw();                 // A(0)
    stage_b(0);                  // B(0)
    write_a(0, 0);               // A(0) -> A0
    if (nt > 1) load_praw();     // A(1)
    __syncthreads();

    for (int ts = 0; ts < nt; ++ts) {
        const int cur = ts & 1;
        if (ts + 1 < nt) {
            stage_b(cur ^ 1);
            write_a(cur ^ 1, (ts + 1) << 5);
            if (ts + 2 < nt) load_praw();
        }
        const char* Ac = lds + cur * 8192;
        const char* Bc = lds + 16384 + cur * 8192;
        __builtin_amdgcn_s_setprio(1);
        {
            bfx8 af[4], bv[4];
#pragma unroll
            for (int m = 0; m < 4; ++m)
                af[m] = __builtin_bit_cast(bfx8, *(const s16x8*)(Ac + a_off[m]));
#pragma unroll
            for (int n = 0; n < 4; ++n)
                bv[n] = __builtin_bit_cast(bfx8, *(const s16x8*)(Bc + b_off[n]));
#pragma unroll
            for (int m = 0; m < 4; ++m)
#pragma unroll
                for (int n = 0; n < 4; ++n)
                    acc[m][n] = __builtin_amdgcn_mfma_f32_16x16x32_bf16(af[m], bv[n], acc[m][n], 0, 0, 0);
        }
        __builtin_amdgcn_s_setprio(0);
        __syncthreads();
    }
#pragma unroll
    for (int n = 0; n < 4; ++n) {
        int nc = n0 + Wc + n * 16 + (l & 15);
        float bs = bias[nc];
        double s = 0.0, q = 0.0;
#pragma unroll
        for (int m = 0; m < 4; ++m) {
            int rbase = m0 + Wr + m * 16 + ((l >> 4) << 2);
#pragma unroll
            for (int i = 0; i < 4; ++i) {
                float v = acc[m][n][i] + bs;
                C[(size_t)(rbase + i) * N + nc] = f2bf(v);
                s += (double)v;
                q += (double)v * (double)v;
            }
        }
        s += __shfl_xor(s, 16, 64); s += __shfl_xor(s, 32, 64);
        q += __shfl_xor(q, 16, 64); q += __shfl_xor(q, 32, 64);
        if ((l >> 4) == 0) {
            atomicAdd(&stats[nc], s);
            atomicAdd(&stats[N + nc], q);
        }
    }
}

// ---------------- final: bn3+ReLU on raw h3, dot w_out, + wide linear, sigmoid ----------------
__global__ void k_out(const unsigned short* __restrict__ h3, const double* __restrict__ stats3,
                      const float* __restrict__ g3, const float* __restrict__ be3,
                      const float* __restrict__ wo, const float* __restrict__ bo,
                      const int* __restrict__ x, const float* __restrict__ lt,
                      const float* __restrict__ lb, float* __restrict__ out) {
    __shared__ float scs[256], shs[256];
    int t = threadIdx.x;
    {
        constexpr double inv_bb = 1.0 / (double)BB;
        double mu = stats3[t] * inv_bb;
        double var = stats3[256 + t] * inv_bb - mu * mu;
        float sc = g3[t] / sqrtf((float)var + EPS_);
        scs[t] = sc;
        shs[t] = be3[t] - (float)mu * sc;
    }
    __syncthreads();
    int r = blockIdx.x * 4 + (t >> 6);
    int lane = t & 63;
    float s = 0.f;
#pragma unroll
    for (int k = lane; k < 256; k += 64) {
        float xv = bf2f(h3[(size_t)r * 256 + k]);
        float hb = bf2f(f2bf(fmaxf(fmaf(xv, scs[k], shs[k]), 0.f)));
        s += hb * wo[k];
    }
    if (lane < NF) {
        long long id = (long long)x[r * NF + lane] + (long long)lane * FIELD_DIM;
        s += lt[id];
    }
#pragma unroll
    for (int off = 32; off > 0; off >>= 1) s += __shfl_xor(s, off, 64);
    if (lane == 0) {
        float tt = s + bo[0] + lb[0];
        out[r] = 1.f / (1.f + expf(-tt));
    }
}

extern "C" void kernel_launch(void* const* d_in, const int* in_sizes, int n_in,
                              void* d_out, int out_size, void* d_ws, size_t ws_size,
                              hipStream_t stream) {
    const int* x = (const int*)d_in[0];
    const float* emb = (const float*)d_in[1];
    const float* lint = (const float*)d_in[2];
    const float* linb = (const float*)d_in[3];
    const float* bng = (const float*)d_in[4];
    const float* bnb = (const float*)d_in[5];
    const float* cw = (const float*)d_in[6];
    const float* cb = (const float*)d_in[7];
    const float* cbg = (const float*)d_in[8];
    const float* cbb = (const float*)d_in[9];
    const float* w1 = (const float*)d_in[10];
    const float* b1 = (const float*)d_in[11];
    const float* g1 = (const float*)d_in[12];
    const float* be1 = (const float*)d_in[13];
    const float* w2 = (const float*)d_in[14];
    const float* b2 = (const float*)d_in[15];
    const float* g2 = (const float*)d_in[16];
    const float* be2 = (const float*)d_in[17];
    const float* w3 = (const float*)d_in[18];
    const float* b3 = (const float*)d_in[19];
    const float* g3 = (const float*)d_in[20];
    const float* be3 = (const float*)d_in[21];
    const float* wo = (const float*)d_in[22];
    const float* bo = (const float*)d_in[23];
    const int* kptr = (const int*)d_in[24];
    float* out = (float*)d_out;

    char* p = (char*)d_ws;
    unsigned short* flatg = (unsigned short*)p; p += (size_t)BB * 640 * 2;  // gated bf16, K-padded
    unsigned short* h1 = (unsigned short*)p; p += (size_t)BB * 1024 * 2;    // raw (pre-BN)
    unsigned short* h2 = (unsigned short*)p; p += (size_t)BB * 512 * 2;     // raw
    unsigned short* h3 = (unsigned short*)p; p += (size_t)BB * 256 * 2;     // raw
    unsigned short* w1t = (unsigned short*)p; p += (size_t)1024 * 640 * 2;
    unsigned short* w2t = (unsigned short*)p; p += (size_t)512 * 1024 * 2;
    unsigned short* w3t = (unsigned short*)p; p += (size_t)256 * 512 * 2;
    float* wct = (float*)p;                  p += (size_t)48 * ND * 4;      // ctrl w transposed fp32
    float* zc = (float*)p;                   p += (size_t)BB * NF * 4;
    double* zp = (double*)p;                 p += (size_t)4 * BB * NF * 8;  // split-K x4 partials fp64
    double* stats_all = (double*)p;
    double* stats_f = stats_all;             // 2*39
    double* stats_c = stats_f + 2 * NF;      // 2*39
    double* stats_1 = stats_c + 2 * NF;      // 2*1024
    double* stats_2 = stats_1 + 2 * 1024;    // 2*512
    double* stats_3 = stats_2 + 2 * 512;     // 2*256
    int stats_doubles = 2 * (NF + NF + 1024 + 512 + 256); // 3662

    // ---- zero all stat regions (must precede k_prep_stats) ----
    hipMemsetAsync(stats_all, 0, stats_doubles * sizeof(double), stream);

    // ---- merged prep + field stats ----
    k_prep_stats<<<3893, 256, 0, stream>>>(x, emb, w1, w2, w3, cw,
                                           w1t, w2t, w3t, wct, stats_f);

    // ---- controller: gather-fused split-K x4 GEMM + reduce/stats + fused finalize/topk/gate ----
    k_ctrl_gemm_sk<<<1024, 256, 0, stream>>>(x, emb, stats_f, bng, bnb, wct, zp);
    k_ctrl_reduce<<<BB / 64, 256, 0, stream>>>(zp, cb, zc, stats_c);
    k_topk_gate<<<BB / 4, 256, 0, stream>>>(zc, stats_c, cbg, cbb, kptr, x, emb,
                                            stats_f, bng, bnb, flatg);

    // ---- MLP layer 1: 640(pad) -> 1024 (h1 raw), BK=64 pipeline ----
    k_mfma_gemm<<<(1024 / 128) * (BB / 128), 256, 0, stream>>>(flatg, w1t, b1, h1, stats_1,
                                                               BB, 640, 1024, 3);

    // ---- MLP layer 2: BN1+ReLU fused into A-staging; 1024 -> 512 (h2 raw), BK=32 4 blk/CU ----
    k_mfma_gemm_bn<<<(512 / 128) * (BB / 128), 256, 0, stream>>>(h1, stats_1, g1, be1,
                                                                 w2t, b2, h2, stats_2,
                                                                 BB, 1024, 512, 2);

    // ---- MLP layer 3: BN2+ReLU fused; 512 -> 256 (h3 raw), BK=32 ----
    k_mfma_gemm_bn<<<(256 / 128) * (BB / 128), 256, 0, stream>>>(h2, stats_2, g2, be2,
                                                                 w3t, b3, h3, stats_3,
                                                                 BB, 512, 256, 1);

    // ---- output: BN3+ReLU + dot w_out + wide linear + sigmoid ----
    k_out<<<BB / 4, 256, 0, stream>>>(h3, stats_3, g3, be3, wo, bo, x, lint, linb, out);
}

// Round 20
// 208.669 us; speedup vs baseline: 1.0633x; 1.0633x over previous
//
#include <hip/hip_runtime.h>
#include <math.h>
#include <stdint.h>

constexpr int BB = 16384;   // batch
constexpr int NF = 39;      // fields
constexpr int NE = 16;      // embed dim
constexpr int ND = NF * NE; // 624
constexpr int FIELD_DIM = 26000;
constexpr float EPS_ = 1e-5f;

typedef __bf16 bfx8 __attribute__((ext_vector_type(8)));
typedef float f32x4 __attribute__((ext_vector_type(4)));
typedef short s16x8 __attribute__((ext_vector_type(8)));

static __device__ __forceinline__ unsigned short f2bf(float f) {
    union { float f; unsigned u; } a; a.f = f;
    unsigned r = a.u + 0x7fffu + ((a.u >> 16) & 1u); // RNE
    return (unsigned short)(r >> 16);
}
static __device__ __forceinline__ float bf2f(unsigned short u) {
    union { unsigned u; float f; } a; a.u = ((unsigned)u) << 16;
    return a.f;
}

// XCD-aware block remap: l -> (bx, by). ny must be 128 (=8 XCDs * 16 panels).
static __device__ __forceinline__ void xcd_map(int l, int lognx, int& bx, int& by) {
    int s = l >> 3;
    bx = s & ((1 << lognx) - 1);
    by = ((l & 7) << 4) + (s >> lognx);
}

// ---------------- merged prep + field-BN stats ----------------
// blocks [0,2496): field stats | [2496,3776): w transposes | [3776,3893): wct
__global__ void k_prep_stats(const int* __restrict__ x, const float* __restrict__ emb,
                             const float* __restrict__ w1, const float* __restrict__ w2,
                             const float* __restrict__ w3, const float* __restrict__ cw,
                             unsigned short* __restrict__ w1t, unsigned short* __restrict__ w2t,
                             unsigned short* __restrict__ w3t, float* __restrict__ wct,
                             double* __restrict__ stats_f) {
    __shared__ double ls[256], lq[256];
    __shared__ float tile[32][33];
    int b = blockIdx.x;
    if (b < 2496) {                       // field stats: f = b%NF, chunk = b/NF
        int f = b % NF;
        int r = (b / NF) * 256 + threadIdx.x;
        double s = 0.0, q = 0.0;
        {
            long long id = (long long)x[r * NF + f] + (long long)f * FIELD_DIM;
            const float4* p = (const float4*)(emb + id * NE);
#pragma unroll
            for (int i = 0; i < 4; ++i) {
                float4 v = p[i];
                s += (double)v.x; s += (double)v.y; s += (double)v.z; s += (double)v.w;
                q += (double)v.x * v.x; q += (double)v.y * v.y;
                q += (double)v.z * v.z; q += (double)v.w * v.w;
            }
        }
        ls[threadIdx.x] = s; lq[threadIdx.x] = q;
        __syncthreads();
        for (int off = 128; off > 0; off >>= 1) {
            if ((int)threadIdx.x < off) {
                ls[threadIdx.x] += ls[threadIdx.x + off];
                lq[threadIdx.x] += lq[threadIdx.x + off];
            }
            __syncthreads();
        }
        if (threadIdx.x == 0) {
            atomicAdd(&stats_f[f], ls[0]);
            atomicAdd(&stats_f[NF + f], lq[0]);
        }
    } else if (b < 3776) {                // LDS-tiled weight transposes
        int bb = b - 2496;
        const float* in; unsigned short* outp; int K, N, Kpad, tid;
        if (bb < 640)       { in = w1; outp = w1t; K = 624;  N = 1024; Kpad = 640;  tid = bb; }
        else if (bb < 1152) { in = w2; outp = w2t; K = 1024; N = 512;  Kpad = 1024; tid = bb - 640; }
        else                { in = w3; outp = w3t; K = 512;  N = 256;  Kpad = 512;  tid = bb - 1152; }
        int tiles_n = N >> 5;
        int tk = tid / tiles_n, tn = tid % tiles_n;
        int tx = threadIdx.x & 31, ty = threadIdx.x >> 5;  // 32 x 8
#pragma unroll
        for (int i = 0; i < 4; ++i) {
            int k = tk * 32 + ty + i * 8, n = tn * 32 + tx;
            tile[ty + i * 8][tx] = (k < K) ? in[(size_t)k * N + n] : 0.f;
        }
        __syncthreads();
#pragma unroll
        for (int i = 0; i < 4; ++i) {
            int n = tn * 32 + ty + i * 8, k = tk * 32 + tx;
            outp[(size_t)n * Kpad + k] = f2bf(tile[tx][ty + i * 8]);
        }
    } else {                              // wct: (48, 624) fp32, rows>=39 zero
        int gid = (b - 3776) * 256 + threadIdx.x;
        if (gid < 48 * ND) {
            int j = gid / ND, k = gid % ND;
            wct[gid] = (j < NF) ? cw[(size_t)k * NF + j] : 0.f;
        }
    }
}

// ---------------- controller GEMM split-K x4, gather-fused A ----------------
__launch_bounds__(256)
__global__ void k_ctrl_gemm_sk(const int* __restrict__ x, const float* __restrict__ emb,
                               const double* __restrict__ stats_f,
                               const float* __restrict__ bng, const float* __restrict__ bnb,
                               const float* __restrict__ wct, double* __restrict__ zp) {
    __shared__ float As[64][68];       // [row][kk], padded
    __shared__ float Ws[64][49];       // [kk][col]
    __shared__ int xoff[64 * NF];      // per-(row,field) emb float-offset
    __shared__ float fsc[NF], fsh[NF];
    const int t = threadIdx.x;
    const int tn = t & 15;             // col group: cols 3tn..3tn+2
    const int tm = t >> 4;             // row group: rows 4tm..4tm+3
    const int bm = blockIdx.x & 255;
    const int qt = blockIdx.x >> 8;    // 0..3
    const int m0 = bm * 64;
    const int kbq[5] = {0, 192, 320, 512, 624};
    const int kbeg = kbq[qt];
    const int kend = kbq[qt + 1];

    if (t < NF) {
        double cnt = (double)BB * NE;
        double mu = stats_f[t] / cnt;
        double var = stats_f[NF + t] / cnt - mu * mu;
        float sc = (float)((double)bng[t] / sqrt(var + (double)EPS_));
        fsc[t] = sc;
        fsh[t] = bnb[t] - (float)mu * sc;
    }
    const int* xrow = x + m0 * NF;
    for (int j = t; j < 64 * NF; j += 256) {
        int f = j % NF;
        xoff[j] = (xrow[j] + f * FIELD_DIM) * NE;
    }
    __syncthreads();

    double acc[4][3] = {};
    for (int k0 = kbeg; k0 < kend; k0 += 64) {
        const int kl = (kend - k0 >= 64) ? 64 : (kend - k0);   // 64 or 48
        const int kl4 = kl >> 2;
#pragma unroll
        for (int i = 0; i < 4; ++i) {
            int idx = t + 256 * i;     // 0..1023
            int row = idx >> 4, c4 = idx & 15;
            if (c4 < kl4) {
                int k = k0 + c4 * 4;
                int f = k >> 4;
                float4 v = *(const float4*)(emb + xoff[row * NF + f] + (k & 12));
                float sc = fsc[f], sh = fsh[f];
                float4 nv = make_float4(fmaf(v.x, sc, sh), fmaf(v.y, sc, sh),
                                        fmaf(v.z, sc, sh), fmaf(v.w, sc, sh));
                *(float4*)&As[row][c4 * 4] = nv;
            }
        }
        {
            int col = t >> 4;          // 0..15
            int c4 = t & 15;
#pragma unroll
            for (int cp = 0; cp < 3; ++cp, col += 16) {
                if (c4 < kl4) {
                    float4 v = *(const float4*)(wct + (size_t)col * ND + k0 + c4 * 4);
                    Ws[c4 * 4 + 0][col] = v.x; Ws[c4 * 4 + 1][col] = v.y;
                    Ws[c4 * 4 + 2][col] = v.z; Ws[c4 * 4 + 3][col] = v.w;
                }
            }
        }
        __syncthreads();
#pragma unroll 4
        for (int kk = 0; kk < kl; ++kk) {
            double a0 = (double)As[4 * tm + 0][kk];
            double a1 = (double)As[4 * tm + 1][kk];
            double a2 = (double)As[4 * tm + 2][kk];
            double a3 = (double)As[4 * tm + 3][kk];
            double w0 = (double)Ws[kk][3 * tn + 0];
            double w1 = (double)Ws[kk][3 * tn + 1];
            double w2 = (double)Ws[kk][3 * tn + 2];
            acc[0][0] += a0 * w0; acc[0][1] += a0 * w1; acc[0][2] += a0 * w2;
            acc[1][0] += a1 * w0; acc[1][1] += a1 * w1; acc[1][2] += a1 * w2;
            acc[2][0] += a2 * w0; acc[2][1] += a2 * w1; acc[2][2] += a2 * w2;
            acc[3][0] += a3 * w0; acc[3][1] += a3 * w1; acc[3][2] += a3 * w2;
        }
        __syncthreads();
    }
    double* zph = zp + (size_t)qt * BB * NF;
#pragma unroll
    for (int j = 0; j < 3; ++j) {
        int col = 3 * tn + j;
        if (col < NF) {
#pragma unroll
            for (int i = 0; i < 4; ++i)
                zph[(size_t)(m0 + 4 * tm + i) * NF + col] = acc[i][j];
        }
    }
}

// ---------------- split-K reduce: z = (float)(((p0+p1)+(p2+p3))+bias), fused col stats --------
__global__ void k_ctrl_reduce(const double* __restrict__ zp, const float* __restrict__ bias,
                              float* __restrict__ z, double* __restrict__ stats) {
    __shared__ double Sred[2][16][48];
    const int t = threadIdx.x;
    const int tn = t & 15;
    const int tm = t >> 4;
    const int m0 = blockIdx.x * 64;
    const size_t H = (size_t)BB * NF;
#pragma unroll
    for (int j = 0; j < 3; ++j) {
        int col = 3 * tn + j;
        double s = 0.0, q = 0.0;
        if (col < NF) {
            float bs = bias[col];
#pragma unroll
            for (int i = 0; i < 4; ++i) {
                size_t idx = (size_t)(m0 + 4 * tm + i) * NF + col;
                double p01 = (zp[idx] + zp[H + idx]) + (zp[2 * H + idx] + zp[3 * H + idx]);
                float v = (float)(p01 + (double)bs);
                z[idx] = v;
                s += (double)v;
                q += (double)v * (double)v;
            }
        }
        Sred[0][tm][col] = s;
        Sred[1][tm][col] = q;
    }
    __syncthreads();
    if (t < NF) {
        double ts = 0.0, tq = 0.0;
#pragma unroll
        for (int i = 0; i < 16; ++i) { ts += Sred[0][i][t]; tq += Sred[1][i][t]; }
        atomicAdd(&stats[t], ts);
        atomicAdd(&stats[NF + t], tq);
    }
}

// ---------------- ctrl-BN finalize + BN+ReLU + rank top-k + gather-gate -> flatg (fused) --------
__global__ void k_topk_gate(const float* __restrict__ zc, const double* __restrict__ stats,
                            const float* __restrict__ cbg, const float* __restrict__ cbb,
                            const int* __restrict__ kptr, const int* __restrict__ x,
                            const float* __restrict__ emb, const double* __restrict__ stats_f,
                            const float* __restrict__ bng, const float* __restrict__ bnb,
                            unsigned short* __restrict__ flatg) {
    __shared__ float sc_s[NF], sh_s[NF], fsc[NF], fsh[NF];
    int t = threadIdx.x;
    if (t < NF) {
        double mu = stats[t] / (double)BB;
        double var = stats[NF + t] / (double)BB - mu * mu;
        float sc = (float)((double)cbg[t] / sqrt(var + (double)EPS_));
        sc_s[t] = sc;
        sh_s[t] = cbb[t] - (float)mu * sc;
        double cnt = (double)BB * NE;
        double muf = stats_f[t] / cnt;
        double varf = stats_f[NF + t] / cnt - muf * muf;
        float scf = (float)((double)bng[t] / sqrt(varf + (double)EPS_));
        fsc[t] = scf;
        fsh[t] = bnb[t] - (float)muf * scf;
    }
    __syncthreads();
    int r = blockIdx.x * 4 + (t >> 6);
    int lane = t & 63;
    int k = kptr[0];
    bool active = (lane < NF);
    float w = -1.f;
    if (active) {
        float v = zc[(size_t)r * NF + lane];
        w = fmaxf(fmaf(v, sc_s[lane], sh_s[lane]), 0.f);
    }
    int rank = 0;
#pragma unroll
    for (int j = 0; j < NF; ++j) {
        float vj = __shfl(w, j, 64);
        rank += (vj > w || (vj == w && j < lane)) ? 1 : 0;
    }
    bool sel = active && (rank < k);
    float val = sel ? w : 0.f;
    float sum = val;
#pragma unroll
    for (int off = 32; off > 0; off >>= 1) sum += __shfl_xor(sum, off, 64);
    if (active) {
        float ms = sel ? ((sum > 0.f) ? (w / sum) : 0.f) : 0.f;
        int o = (x[r * NF + lane] + lane * FIELD_DIM) * NE;
        const float4* pe = (const float4*)(emb + o);
        float sc = fsc[lane], sh = fsh[lane];
        unsigned short* dst = flatg + (size_t)r * 640 + lane * 16;
#pragma unroll
        for (int h = 0; h < 2; ++h) {
            float4 e0 = pe[h * 2], e1 = pe[h * 2 + 1];
            float e[8] = {e0.x, e0.y, e0.z, e0.w, e1.x, e1.y, e1.z, e1.w};
            union { s16x8 v; unsigned short u[8]; } p;
#pragma unroll
            for (int j = 0; j < 8; ++j)
                p.u[j] = f2bf(fmaf(e[j], sc, sh) * ms);   // same op order as flat path
            *(s16x8*)(dst + h * 8) = p.v;
        }
    } else if (lane == NF) {
        s16x8 zv = {};
        *(s16x8*)(flatg + (size_t)r * 640 + 624) = zv;
        *(s16x8*)(flatg + (size_t)r * 640 + 632) = zv;
    }
}

// ---------------- bf16 MFMA GEMM (layer 1): 2-phase double-buffered + T5 setprio ----------------
__launch_bounds__(256)
__global__ void k_mfma_gemm(const unsigned short* __restrict__ A,  // M x K bf16
                            const unsigned short* __restrict__ Bt, // N x K bf16
                            const float* __restrict__ bias,
                            unsigned short* __restrict__ C,        // M x N bf16
                            double* __restrict__ stats,            // 2*N fp64
                            int M, int K, int N, int lognx) {
    __shared__ char lds[65536];   // A0 A1 B0 B1, 16KB each
    const int t = threadIdx.x;
    const int l = t & 63;
    const int w = t >> 6;
    int bx, by;
    xcd_map(blockIdx.x, lognx, bx, by);
    const int m0 = by * 128, n0 = bx * 128;
    const int Wr = (w >> 1) * 64, Wc = (w & 1) * 64;

    const int srow = t >> 3;            // 0..31
    const int sswz = (t & 7) ^ (srow & 7);
    const unsigned short* ga[4];
    const unsigned short* gb[4];
#pragma unroll
    for (int i = 0; i < 4; ++i) {
        ga[i] = A + (size_t)(m0 + i * 32 + srow) * K + sswz * 8;
        gb[i] = Bt + (size_t)(n0 + i * 32 + srow) * K + sswz * 8;
    }
    int a_off[4][2], b_off[4][2];
#pragma unroll
    for (int m = 0; m < 4; ++m) {
#pragma unroll
        for (int h = 0; h < 2; ++h) {
            int r = Wr + m * 16 + (l & 15);
            a_off[m][h] = r * 128 + (((h * 4 + (l >> 4)) ^ (r & 7)) << 4);
            int c = Wc + m * 16 + (l & 15);
            b_off[m][h] = c * 128 + (((h * 4 + (l >> 4)) ^ (c & 7)) << 4);
        }
    }
    const int nt = K >> 6;
    f32x4 acc[4][4] = {};
#pragma unroll
    for (int i = 0; i < 4; ++i) {
        __builtin_amdgcn_global_load_lds(
            (const __attribute__((address_space(1))) void*)ga[i],
            (__attribute__((address_space(3))) void*)(lds + i * 4096 + t * 16), 16, 0, 0);
        __builtin_amdgcn_global_load_lds(
            (const __attribute__((address_space(1))) void*)gb[i],
            (__attribute__((address_space(3))) void*)(lds + 32768 + i * 4096 + t * 16), 16, 0, 0);
        ga[i] += 64; gb[i] += 64;
    }
    __syncthreads();
    for (int ts = 0; ts < nt; ++ts) {
        const int cur = ts & 1;
        if (ts + 1 < nt) {
            char* An = lds + (cur ^ 1) * 16384;
            char* Bn = lds + 32768 + (cur ^ 1) * 16384;
#pragma unroll
            for (int i = 0; i < 4; ++i) {
                __builtin_amdgcn_global_load_lds(
                    (const __attribute__((address_space(1))) void*)ga[i],
                    (__attribute__((address_space(3))) void*)(An + i * 4096 + t * 16), 16, 0, 0);
                __builtin_amdgcn_global_load_lds(
                    (const __attribute__((address_space(1))) void*)gb[i],
                    (__attribute__((address_space(3))) void*)(Bn + i * 4096 + t * 16), 16, 0, 0);
                ga[i] += 64; gb[i] += 64;
            }
        }
        const char* Ac = lds + cur * 16384;
        const char* Bc = lds + 32768 + cur * 16384;
        __builtin_amdgcn_s_setprio(1);
#pragma unroll
        for (int h = 0; h < 2; ++h) {
            bfx8 af[4], bv[4];
#pragma unroll
            for (int m = 0; m < 4; ++m)
                af[m] = __builtin_bit_cast(bfx8, *(const s16x8*)(Ac + a_off[m][h]));
#pragma unroll
            for (int n = 0; n < 4; ++n)
                bv[n] = __builtin_bit_cast(bfx8, *(const s16x8*)(Bc + b_off[n][h]));
#pragma unroll
            for (int m = 0; m < 4; ++m)
#pragma unroll
                for (int n = 0; n < 4; ++n)
                    acc[m][n] = __builtin_amdgcn_mfma_f32_16x16x32_bf16(af[m], bv[n], acc[m][n], 0, 0, 0);
        }
        __builtin_amdgcn_s_setprio(0);
        __syncthreads();
    }
#pragma unroll
    for (int n = 0; n < 4; ++n) {
        int nc = n0 + Wc + n * 16 + (l & 15);
        float bs = bias[nc];
        double s = 0.0, q = 0.0;
#pragma unroll
        for (int m = 0; m < 4; ++m) {
            int rbase = m0 + Wr + m * 16 + ((l >> 4) << 2);
#pragma unroll
            for (int i = 0; i < 4; ++i) {
                float v = acc[m][n][i] + bs;
                C[(size_t)(rbase + i) * N + nc] = f2bf(v);
                s += (double)v;
                q += (double)v * (double)v;
            }
        }
        s += __shfl_xor(s, 16, 64); s += __shfl_xor(s, 32, 64);
        q += __shfl_xor(q, 16, 64); q += __shfl_xor(q, 32, 64);
        if ((l >> 4) == 0) {
            atomicAdd(&stats[nc], s);
            atomicAdd(&stats[N + nc], q);
        }
    }
}

// ---------------- bf16 MFMA GEMM with fused input-BN+ReLU on A (layers 2,3), BK=64 ----------
__launch_bounds__(256)
__global__ void k_mfma_gemm_bn(const unsigned short* __restrict__ A,   // M x K bf16 raw
                               const double* __restrict__ statsIn,     // 2*K (A's BN stats)
                               const float* __restrict__ g, const float* __restrict__ be,
                               const unsigned short* __restrict__ Bt,  // N x K bf16
                               const float* __restrict__ bias,
                               unsigned short* __restrict__ C,         // M x N bf16
                               double* __restrict__ stats,             // 2*N fp64
                               int M, int K, int N, int lognx) {
    __shared__ char lds[73728];           // A0 A1 B0 B1 (16KB each) + scs/shs (8KB)
    float* scs = (float*)(lds + 65536);   // K floats
    float* shs = scs + K;                 // K floats (K<=1024)
    const int t = threadIdx.x;
    const int l = t & 63;
    const int w = t >> 6;
    int bx, by;
    xcd_map(blockIdx.x, lognx, bx, by);
    const int m0 = by * 128, n0 = bx * 128;
    const int Wr = (w >> 1) * 64, Wc = (w & 1) * 64;

    constexpr double inv_bb = 1.0 / (double)BB;
    for (int c = t; c < K; c += 256) {
        double mu = statsIn[c] * inv_bb;
        double var = statsIn[K + c] * inv_bb - mu * mu;
        float sc = g[c] / sqrtf((float)var + EPS_);
        scs[c] = sc;
        shs[c] = be[c] - (float)mu * sc;
    }
    __syncthreads();

    const int srow = t >> 3;            // 0..31
    const int sswz = (t & 7) ^ (srow & 7);
    const unsigned short* ga[4];
    const unsigned short* gb[4];
#pragma unroll
    for (int i = 0; i < 4; ++i) {
        ga[i] = A + (size_t)(m0 + i * 32 + srow) * K + sswz * 8;
        gb[i] = Bt + (size_t)(n0 + i * 32 + srow) * K + sswz * 8;
    }
    int a_off[4][2], b_off[4][2];
#pragma unroll
    for (int m = 0; m < 4; ++m) {
#pragma unroll
        for (int h = 0; h < 2; ++h) {
            int r = Wr + m * 16 + (l & 15);
            a_off[m][h] = r * 128 + (((h * 4 + (l >> 4)) ^ (r & 7)) << 4);
            int c = Wc + m * 16 + (l & 15);
            b_off[m][h] = c * 128 + (((h * 4 + (l >> 4)) ^ (c & 7)) << 4);
        }
    }
    const int nt = K >> 6;
    f32x4 acc[4][4] = {};
    s16x8 praw[4];

    auto write_a = [&](int buf, int kb0) {
        char* Ad = lds + buf * 16384;
        int kb = kb0 + sswz * 8;
        float4 sc0 = *(const float4*)&scs[kb];
        float4 sc1 = *(const float4*)&scs[kb + 4];
        float4 sh0 = *(const float4*)&shs[kb];
        float4 sh1 = *(const float4*)&shs[kb + 4];
        float scl[8] = {sc0.x, sc0.y, sc0.z, sc0.w, sc1.x, sc1.y, sc1.z, sc1.w};
        float shl[8] = {sh0.x, sh0.y, sh0.z, sh0.w, sh1.x, sh1.y, sh1.z, sh1.w};
#pragma unroll
        for (int i = 0; i < 4; ++i) {
            union { s16x8 v; unsigned short u[8]; } pin;
            pin.v = praw[i];
            float f[8];
#pragma unroll
            for (int j = 0; j < 8; ++j)
                f[j] = fmaxf(fmaf(bf2f(pin.u[j]), scl[j], shl[j]), 0.f);
            union { unsigned w4[4]; s16x8 v; } pout;
#pragma unroll
            for (int j = 0; j < 4; ++j) {
                unsigned rr;
                asm("v_cvt_pk_bf16_f32 %0, %1, %2" : "=v"(rr) : "v"(f[2 * j]), "v"(f[2 * j + 1]));
                pout.w4[j] = rr;
            }
            *(s16x8*)(Ad + i * 4096 + t * 16) = pout.v;
        }
    };
    auto load_praw = [&]() {
#pragma unroll
        for (int i = 0; i < 4; ++i) { praw[i] = *(const s16x8*)ga[i]; ga[i] += 64; }
    };
    auto stage_b = [&](int buf) {
        char* Bd = lds + 32768 + buf * 16384;
#pragma unroll
        for (int i = 0; i < 4; ++i) {
            __builtin_amdgcn_global_load_lds(
                (const __attribute__((address_space(1))) void*)gb[i],
                (__attribute__((address_space(3))) void*)(Bd + i * 4096 + t * 16), 16, 0, 0);
            gb[i] += 64;
        }
    };

    load_praw();
    stage_b(0);
    write_a(0, 0);
    if (nt > 1) load_praw();
    __syncthreads();

    for (int ts = 0; ts < nt; ++ts) {
        const int cur = ts & 1;
        if (ts + 1 < nt) {
            stage_b(cur ^ 1);
            write_a(cur ^ 1, (ts + 1) << 6);
            if (ts + 2 < nt) load_praw();
        }
        const char* Ac = lds + cur * 16384;
        const char* Bc = lds + 32768 + cur * 16384;
        __builtin_amdgcn_s_setprio(1);
#pragma unroll
        for (int h = 0; h < 2; ++h) {
            bfx8 af[4], bv[4];
#pragma unroll
            for (int m = 0; m < 4; ++m)
                af[m] = __builtin_bit_cast(bfx8, *(const s16x8*)(Ac + a_off[m][h]));
#pragma unroll
            for (int n = 0; n < 4; ++n)
                bv[n] = __builtin_bit_cast(bfx8, *(const s16x8*)(Bc + b_off[n][h]));
#pragma unroll
            for (int m = 0; m < 4; ++m)
#pragma unroll
                for (int n = 0; n < 4; ++n)
                    acc[m][n] = __builtin_amdgcn_mfma_f32_16x16x32_bf16(af[m], bv[n], acc[m][n], 0, 0, 0);
        }
        __builtin_amdgcn_s_setprio(0);
        __syncthreads();
    }
#pragma unroll
    for (int n = 0; n < 4; ++n) {
        int nc = n0 + Wc + n * 16 + (l & 15);
        float bs = bias[nc];
        double s = 0.0, q = 0.0;
#pragma unroll
        for (int m = 0; m < 4; ++m) {
            int rbase = m0 + Wr + m * 16 + ((l >> 4) << 2);
#pragma unroll
            for (int i = 0; i < 4; ++i) {
                float v = acc[m][n][i] + bs;
                C[(size_t)(rbase + i) * N + nc] = f2bf(v);
                s += (double)v;
                q += (double)v * (double)v;
            }
        }
        s += __shfl_xor(s, 16, 64); s += __shfl_xor(s, 32, 64);
        q += __shfl_xor(q, 16, 64); q += __shfl_xor(q, 32, 64);
        if ((l >> 4) == 0) {
            atomicAdd(&stats[nc], s);
            atomicAdd(&stats[N + nc], q);
        }
    }
}

// ---------------- final: bn3+ReLU on raw h3, dot w_out, + wide linear, sigmoid ----------------
__global__ void k_out(const unsigned short* __restrict__ h3, const double* __restrict__ stats3,
                      const float* __restrict__ g3, const float* __restrict__ be3,
                      const float* __restrict__ wo, const float* __restrict__ bo,
                      const int* __restrict__ x, const float* __restrict__ lt,
                      const float* __restrict__ lb, float* __restrict__ out) {
    __shared__ float scs[256], shs[256];
    int t = threadIdx.x;
    {
        constexpr double inv_bb = 1.0 / (double)BB;
        double mu = stats3[t] * inv_bb;
        double var = stats3[256 + t] * inv_bb - mu * mu;
        float sc = g3[t] / sqrtf((float)var + EPS_);
        scs[t] = sc;
        shs[t] = be3[t] - (float)mu * sc;
    }
    __syncthreads();
    int r = blockIdx.x * 4 + (t >> 6);
    int lane = t & 63;
    float s = 0.f;
#pragma unroll
    for (int k = lane; k < 256; k += 64) {
        float xv = bf2f(h3[(size_t)r * 256 + k]);
        float hb = bf2f(f2bf(fmaxf(fmaf(xv, scs[k], shs[k]), 0.f)));
        s += hb * wo[k];
    }
    if (lane < NF) {
        long long id = (long long)x[r * NF + lane] + (long long)lane * FIELD_DIM;
        s += lt[id];
    }
#pragma unroll
    for (int off = 32; off > 0; off >>= 1) s += __shfl_xor(s, off, 64);
    if (lane == 0) {
        float tt = s + bo[0] + lb[0];
        out[r] = 1.f / (1.f + expf(-tt));
    }
}

extern "C" void kernel_launch(void* const* d_in, const int* in_sizes, int n_in,
                              void* d_out, int out_size, void* d_ws, size_t ws_size,
                              hipStream_t stream) {
    const int* x = (const int*)d_in[0];
    const float* emb = (const float*)d_in[1];
    const float* lint = (const float*)d_in[2];
    const float* linb = (const float*)d_in[3];
    const float* bng = (const float*)d_in[4];
    const float* bnb = (const float*)d_in[5];
    const float* cw = (const float*)d_in[6];
    const float* cb = (const float*)d_in[7];
    const float* cbg = (const float*)d_in[8];
    const float* cbb = (const float*)d_in[9];
    const float* w1 = (const float*)d_in[10];
    const float* b1 = (const float*)d_in[11];
    const float* g1 = (const float*)d_in[12];
    const float* be1 = (const float*)d_in[13];
    const float* w2 = (const float*)d_in[14];
    const float* b2 = (const float*)d_in[15];
    const float* g2 = (const float*)d_in[16];
    const float* be2 = (const float*)d_in[17];
    const float* w3 = (const float*)d_in[18];
    const float* b3 = (const float*)d_in[19];
    const float* g3 = (const float*)d_in[20];
    const float* be3 = (const float*)d_in[21];
    const float* wo = (const float*)d_in[22];
    const float* bo = (const float*)d_in[23];
    const int* kptr = (const int*)d_in[24];
    float* out = (float*)d_out;

    char* p = (char*)d_ws;
    unsigned short* flatg = (unsigned short*)p; p += (size_t)BB * 640 * 2;  // gated bf16, K-padded
    unsigned short* h1 = (unsigned short*)p; p += (size_t)BB * 1024 * 2;    // raw (pre-BN)
    unsigned short* h2 = (unsigned short*)p; p += (size_t)BB * 512 * 2;     // raw
    unsigned short* h3 = (unsigned short*)p; p += (size_t)BB * 256 * 2;     // raw
    unsigned short* w1t = (unsigned short*)p; p += (size_t)1024 * 640 * 2;
    unsigned short* w2t = (unsigned short*)p; p += (size_t)512 * 1024 * 2;
    unsigned short* w3t = (unsigned short*)p; p += (size_t)256 * 512 * 2;
    float* wct = (float*)p;                  p += (size_t)48 * ND * 4;      // ctrl w transposed fp32
    float* zc = (float*)p;                   p += (size_t)BB * NF * 4;
    double* zp = (double*)p;                 p += (size_t)4 * BB * NF * 8;  // split-K x4 partials fp64
    double* stats_all = (double*)p;
    double* stats_f = stats_all;             // 2*39
    double* stats_c = stats_f + 2 * NF;      // 2*39
    double* stats_1 = stats_c + 2 * NF;      // 2*1024
    double* stats_2 = stats_1 + 2 * 1024;    // 2*512
    double* stats_3 = stats_2 + 2 * 512;     // 2*256
    int stats_doubles = 2 * (NF + NF + 1024 + 512 + 256); // 3662

    // ---- zero all stat regions (must precede k_prep_stats) ----
    hipMemsetAsync(stats_all, 0, stats_doubles * sizeof(double), stream);

    // ---- merged prep + field stats ----
    k_prep_stats<<<3893, 256, 0, stream>>>(x, emb, w1, w2, w3, cw,
                                           w1t, w2t, w3t, wct, stats_f);

    // ---- controller: gather-fused split-K x4 GEMM + reduce/stats + fused finalize/topk/gate ----
    k_ctrl_gemm_sk<<<1024, 256, 0, stream>>>(x, emb, stats_f, bng, bnb, wct, zp);
    k_ctrl_reduce<<<BB / 64, 256, 0, stream>>>(zp, cb, zc, stats_c);
    k_topk_gate<<<BB / 4, 256, 0, stream>>>(zc, stats_c, cbg, cbb, kptr, x, emb,
                                            stats_f, bng, bnb, flatg);

    // ---- MLP layer 1: 640(pad) -> 1024 (h1 raw) ----
    k_mfma_gemm<<<(1024 / 128) * (BB / 128), 256, 0, stream>>>(flatg, w1t, b1, h1, stats_1,
                                                               BB, 640, 1024, 3);

    // ---- MLP layer 2: BN1+ReLU fused into A-staging; 1024 -> 512 (h2 raw) ----
    k_mfma_gemm_bn<<<(512 / 128) * (BB / 128), 256, 0, stream>>>(h1, stats_1, g1, be1,
                                                                 w2t, b2, h2, stats_2,
                                                                 BB, 1024, 512, 2);

    // ---- MLP layer 3: BN2+ReLU fused; 512 -> 256 (h3 raw) ----
    k_mfma_gemm_bn<<<(256 / 128) * (BB / 128), 256, 0, stream>>>(h2, stats_2, g2, be2,
                                                                 w3t, b3, h3, stats_3,
                                                                 BB, 512, 256, 1);

    // ---- output: BN3+ReLU + dot w_out + wide linear + sigmoid ----
    k_out<<<BB / 4, 256, 0, stream>>>(h3, stats_3, g3, be3, wo, bo, x, lint, linb, out);
}